// Round 9
// baseline (146.956 us; speedup 1.0000x reference)
//
#include <hip/hip_runtime.h>
#include <math.h>

typedef unsigned long long u64;
typedef unsigned int u32;

// Problem constants (fixed by the reference setup_inputs)
static constexpr int A = 16384;
static constexpr int M = 32;
static constexpr int C = 15;
static constexpr int B = 2;
static constexpr int NBLK = A / 32;            // 512 row-tiles per image
static constexpr int NGATE = B * A * M / 256;  // 4096 gate blocks == geom segments
static constexpr int NLOSS = (A / 256) * B;    // 128

static constexpr double PI_D = 3.14159265358979323846;

// ---- workspace layout (bytes) ----
static constexpr size_t OFF_MD     = 0;                                   // f32[B][A][M]   4MB
static constexpr size_t OFF_LIST   = OFF_MD + (size_t)B*A*M*4;            // u32[NGATE][256] 4MB
static constexpr size_t OFF_SEGC   = OFF_LIST + (size_t)NGATE*256*4;      // u32[NGATE]
static constexpr size_t OFF_PALLT  = OFF_SEGC + (size_t)NGATE*4;          // u64[NBLK][64]  256KB (transposed)
static constexpr size_t OFF_PPOST  = OFF_PALLT + (size_t)NBLK*64*8;       // u64[NBLK][64]  256KB
static constexpr size_t OFF_PCNT   = OFF_PPOST + (size_t)NBLK*64*8;       // u32[B*NBLK]    4KB
static constexpr size_t OFF_IOUMAX = OFF_PCNT + (size_t)B*NBLK*4;         // f32[B][A]
static constexpr size_t OFF_IOUARG = OFF_IOUMAX + (size_t)B*A*4;          // int[B][A]
static constexpr size_t OFF_POS    = OFF_IOUARG + (size_t)B*A*4;          // int[B][A]
static constexpr size_t OFF_NPFIX  = OFF_POS + (size_t)B*A*4;             // int[B]
static constexpr size_t OFF_SUMS   = (OFF_NPFIX + (size_t)B*4 + 7) & ~(size_t)7; // double[4]
static constexpr size_t OFF_DONES  = OFF_SUMS + 4*8;                      // int[1]

// ---------- geometry helpers (all double, fully register-resident) ----------
__device__ inline double aa_square_iou(double cx1, double cy1, double s1,
                                       double cx2, double cy2, double s2) {
    double lx = fmax(cx1 - s1, cx2 - s2), ly = fmax(cy1 - s1, cy2 - s2);
    double rx = fmin(cx1 + s1, cx2 + s2), ry = fmin(cy1 + s1, cy2 + s2);
    double w = fmax(rx - lx, 0.0), h = fmax(ry - ly, 0.0);
    double inter = w * h;
    double aa = (2.0 * s1) * (2.0 * s1);
    double ab = (2.0 * s2) * (2.0 * s2);
    return inter / (aa + ab - inter + 1e-8);
}

__device__ inline void rbox_corners1(double cx, double cy, double w, double h,
                                     double adeg, double* X, double* Y) {
    double t = adeg * (PI_D / 180.0);
    double c = cos(t), s = sin(t);
    const double lx[4] = {-0.5, 0.5, 0.5, -0.5};
    const double ly[4] = {-0.5, -0.5, 0.5, 0.5};
#pragma unroll
    for (int i = 0; i < 4; ++i) {
        double dx = w * lx[i], dy = h * ly[i];
        X[i] = cx + dx * c - dy * s;
        Y[i] = cy + dx * s + dy * c;
    }
}

// Interval-clipped boundary integral: area contribution of P's edges inside Q.
__device__ inline double edges_in_quad_cross_sum(const double* PX, const double* PY,
                                                 const double* QX, const double* QY) {
    double s = 0.0;
#pragma unroll
    for (int k = 0; k < 4; ++k) {
        double x0 = PX[k], y0 = PY[k];
        double x1 = PX[(k + 1) & 3], y1 = PY[(k + 1) & 3];
        double ex = x1 - x0, ey = y1 - y0;
        double t0 = 0.0, t1 = 1.0;
        bool empty = false;
#pragma unroll
        for (int e = 0; e < 4; ++e) {
            double qx0 = QX[e], qy0 = QY[e];
            double qex = QX[(e + 1) & 3] - qx0;
            double qey = QY[(e + 1) & 3] - qy0;
            double d0 = qex * (y0 - qy0) - qey * (x0 - qx0);  // >=0 inside (CCW)
            double d1 = qex * (y1 - qy0) - qey * (x1 - qx0);
            if (d0 < 0.0 && d1 < 0.0) empty = true;
            else if (d0 < 0.0) t0 = fmax(t0, d0 / (d0 - d1));
            else if (d1 < 0.0) t1 = fmin(t1, d0 / (d0 - d1));
        }
        if (!empty && t1 > t0) {
            double ax = x0 + t0 * ex, ay = y0 + t0 * ey;
            double bx = x0 + t1 * ex, by = y0 + t1 * ey;
            s += ax * by - ay * bx;
        }
    }
    return s;
}

__device__ inline double quad_inter_area(const double* AX, const double* AY,
                                         const double* BX, const double* BY) {
    double s = edges_in_quad_cross_sum(AX, AY, BX, BY) +
               edges_in_quad_cross_sum(BX, BY, AX, AY);
    return 0.5 * fabs(s);
}

__device__ inline u64 pack_key(float v, u32 inv_idx) {
    return ((u64)__float_as_uint(v) << 32) | (u64)inv_idx;
}

// ---------- kernels ----------
// 1) Gate all 1M pairs; per-block private compaction segments (no global
//    atomics). Also zeroes sums/dones.
__global__ void k_gate(const float* __restrict__ anc, const float* __restrict__ ranc,
                       const float* __restrict__ ann, float* __restrict__ md,
                       u32* __restrict__ list, u32* __restrict__ segcnt,
                       double* __restrict__ sums, int* __restrict__ dones) {
    __shared__ u32 l_cnt;
    __shared__ u32 l_idx[256];
    int tid = threadIdx.x;
    if (tid == 0) l_cnt = 0;
    __syncthreads();

    int t = blockIdx.x * 256 + tid;
    if (t < 4) sums[t] = 0.0;
    if (t < 1) dones[0] = 0;
    int m = t & (M - 1);
    int a = (t >> 5) & (A - 1);
    int b = t >> 19;

    const float* pa = anc + ((size_t)(b * A + a)) * 5;
    const float* pr = ranc + ((size_t)(b * A + a)) * 5;
    const float* pg = ann + ((size_t)(b * M + m)) * 6;

    double cxg = pg[0], cyg = pg[1];
    double sg = 0.5 * fmax((double)pg[2], (double)pg[3]);
    double i_bf = aa_square_iou(pa[0], pa[1], 0.5 * fmax((double)pa[2], (double)pa[3]),
                                cxg, cyg, sg);
    double i_af = aa_square_iou(pr[0], pr[1], 0.5 * fmax((double)pr[2], (double)pr[3]),
                                cxg, cyg, sg);
    bool g = (i_bf >= 0.1) || (i_af >= 0.1);
    md[t] = 0.0f;  // gated entries overwritten by k_geom

    if (g) {
        u32 s = atomicAdd(&l_cnt, 1u);  // LDS atomic — per-CU, cheap
        l_idx[s] = (u32)t;
    }
    __syncthreads();
    u32 n = l_cnt;
    if ((u32)tid < n) list[blockIdx.x * 256 + tid] = l_idx[tid];
    if (tid == 0) segcnt[blockIdx.x] = n;
}

// 2) Dense geometry: one wave per gate-segment; lanes process segment entries.
__global__ void k_geom(const float* __restrict__ anc, const float* __restrict__ ranc,
                       const float* __restrict__ ann, const u32* __restrict__ list,
                       const u32* __restrict__ segcnt, float* __restrict__ md) {
    int gtid = blockIdx.x * 256 + threadIdx.x;
    int wave = gtid >> 6;         // 0..NGATE-1
    int lane = gtid & 63;
    u32 n = segcnt[wave];
    for (u32 i = lane; i < n; i += 64) {
        u32 t = list[wave * 256 + i];
        int m = t & (M - 1);
        int a = ((int)t >> 5) & (A - 1);
        int b = (int)t >> 19;
        const float* pa = anc + ((size_t)(b * A + a)) * 5;
        const float* pr = ranc + ((size_t)(b * A + a)) * 5;
        const float* pg = ann + ((size_t)(b * M + m)) * 6;

        double cxg = pg[0], cyg = pg[1], wg = pg[2], hg = pg[3], ag = pg[4];
        double sg = 0.5 * fmax(wg, hg);
        double cxa = pa[0], cya = pa[1], wa = pa[2], ha = pa[3], aa = pa[4];
        double cxr = pr[0], cyr = pr[1], wr = pr[2], hr = pr[3], ar = pr[4];

        double i_bf = aa_square_iou(cxa, cya, 0.5 * fmax(wa, ha), cxg, cyg, sg);
        double i_af = aa_square_iou(cxr, cyr, 0.5 * fmax(wr, hr), cxg, cyg, sg);

        double GX[4], GY[4];
        rbox_corners1(cxg, cyg, wg, hg, ag, GX, GY);
        double areaG = wg * hg;
        double ov_bf = 0.0, ov_af = 0.0;
        if (i_bf >= 0.1) {
            double X[4], Y[4];
            rbox_corners1(cxa, cya, wa, ha, aa, X, Y);
            double inter = quad_inter_area(X, Y, GX, GY);
            ov_bf = inter / (wa * ha + areaG - inter + 1e-8);
        }
        if (i_af >= 0.1) {
            double X[4], Y[4];
            rbox_corners1(cxr, cyr, wr, hr, ar, X, Y);
            double inter = quad_inter_area(X, Y, GX, GY);
            ov_af = inter / (wr * hr + areaG - inter + 1e-8);
        }
        md[t] = (float)fabs(ov_bf + 0.5 * ov_af - fabs(ov_af - ov_bf));
    }
}

// 3) Assignment: per-tile row max/argmax/pos + transposed column partials +
//    pos counts. PLAIN writes only — zero global atomics (r8's atomicMax tail
//    cost ~5-10us of serialized RMWs; r7's fence tail cost 113us).
__global__ void k_assign(const float* __restrict__ md,
                         float* __restrict__ iou_max, int* __restrict__ iou_arg,
                         int* __restrict__ pos, u64* __restrict__ pAllT,
                         u64* __restrict__ pPosT, u32* __restrict__ pCnt) {
    int blk = blockIdx.x, b = blockIdx.y, tid = threadIdx.x;
    int a0 = blk * 32;
    const float4* src = (const float4*)(md + (size_t)(b * A + a0) * M);
    float4 v4 = src[tid];                       // tile [32 rows][32 cols]
    int rr = tid >> 3, c0 = (tid & 7) * 4;
    float vv[4] = {v4.x, v4.y, v4.z, v4.w};

    u64 rowk = 0;
#pragma unroll
    for (int j = 0; j < 4; ++j) {
        u64 k = pack_key(vv[j], 0xFFFFFFFFu - (u32)(c0 + j));
        if (k > rowk) rowk = k;
    }
#pragma unroll
    for (int off = 1; off < 8; off <<= 1) {
        u64 o = __shfl_xor(rowk, off, 8);
        if (o > rowk) rowk = o;
    }
    float rmax = __uint_as_float((u32)(rowk >> 32));
    int p = (rmax >= 0.5f) ? 1 : 0;

    __shared__ u64 lAll[32][33];
    __shared__ u64 lPos[32][33];
    __shared__ int lcnt[32];
    u32 inva = 0xFFFFFFFFu - (u32)(a0 + rr);
#pragma unroll
    for (int j = 0; j < 4; ++j) {
        u64 ck = pack_key(vv[j], inva);
        lAll[rr][c0 + j] = ck;
        lPos[rr][c0 + j] = p ? ck : 0ull;
    }
    if ((tid & 7) == 0) {
        int idx = b * A + a0 + rr;
        iou_max[idx] = rmax;
        iou_arg[idx] = (int)(0xFFFFFFFFu - (u32)(rowk & 0xFFFFFFFFull));
        pos[idx] = p;
        lcnt[rr] = p;
    }
    __syncthreads();
    if (tid < 32) {
        u64 ka = 0, kp = 0;
#pragma unroll
        for (int r = 0; r < 32; ++r) {
            u64 x = lAll[r][tid]; if (x > ka) ka = x;
            u64 y = lPos[r][tid]; if (y > kp) kp = y;
        }
        pAllT[(size_t)blk * 64 + b * 32 + tid] = ka;   // transposed: coalesced reduce
        pPosT[(size_t)blk * 64 + b * 32 + tid] = kp;
        if (tid == 0) {
            int c = 0;
#pragma unroll
            for (int r = 0; r < 32; ++r) c += lcnt[r];
            pCnt[b * NBLK + blk] = (u32)c;
        }
    }
}

// 4) Loss + final combine. Each block independently reduces the column
//    partials (L2-resident, ~256KB) to rebuild keyAll/keyPos/forced-list in
//    LDS — deterministic, no cross-block sync. Final combine via relaxed flag
//    (r8-proven: __syncthreads drains vmcnt before the flag add).
__global__ void k_loss(const float* __restrict__ cls_in, const float* __restrict__ reg_in,
                       const float* __restrict__ anc, const float* __restrict__ ann,
                       const float* __restrict__ md,
                       const float* __restrict__ iou_max, const int* __restrict__ iou_arg,
                       const int* __restrict__ pos,
                       const u64* __restrict__ pAllT, const u64* __restrict__ pPosT,
                       const u32* __restrict__ pCnt, int* __restrict__ npfix,
                       double* __restrict__ sums, int* __restrict__ dones,
                       float* __restrict__ out) {
    int b = blockIdx.y;
    int tid = threadIdx.x;
    int a = blockIdx.x * 256 + tid;

    // ---- prologue: reduce column partials for this image ----
    __shared__ u64 redA[8][32];
    __shared__ u64 redP[8][32];
    {
        int grp = tid >> 5, l32 = tid & 31;
        u64 ka = 0, kp = 0;
        for (int t2 = grp; t2 < NBLK; t2 += 8) {
            u64 x = pAllT[(size_t)t2 * 64 + b * 32 + l32]; if (x > ka) ka = x;
            u64 y = pPosT[(size_t)t2 * 64 + b * 32 + l32]; if (y > kp) kp = y;
        }
        redA[grp][l32] = ka;
        redP[grp][l32] = kp;
    }
    __syncthreads();

    __shared__ int s_fl[M];
    __shared__ float s_maxpos[M];
    __shared__ int s_argpos[M];
    __shared__ u64 s_kpos[M];
    if (tid < M) {
        u64 kall = redA[0][tid], kp = redP[0][tid];
#pragma unroll
        for (int g2 = 1; g2 < 8; ++g2) {
            u64 x = redA[g2][tid]; if (x > kall) kall = x;
            u64 y = redP[g2][tid]; if (y > kp) kp = y;
        }
        float mx = __uint_as_float((u32)(kall >> 32));
        s_fl[tid] = (mx < 0.5f) ? (int)(0xFFFFFFFFu - (u32)(kall & 0xFFFFFFFFull)) : -1;
        s_kpos[tid] = kp;
    }
    __syncthreads();
    if (tid < M) {
        u64 kp = s_kpos[tid];
        for (int f = 0; f < M; ++f) {
            int fa = s_fl[f];
            if (fa >= 0) {
                float v = md[((size_t)(b * A + fa)) * M + tid];
                u64 k = pack_key(v, 0xFFFFFFFFu - (u32)fa);
                if (k > kp) kp = k;
            }
        }
        if (kp == 0ull) { s_maxpos[tid] = 0.0f; s_argpos[tid] = -1; }
        else {
            s_maxpos[tid] = __uint_as_float((u32)(kp >> 32));
            s_argpos[tid] = (int)(0xFFFFFFFFu - (u32)(kp & 0xFFFFFFFFull));
        }
    }
    __syncthreads();

    // image num_pos (block x==0 only): pCnt sum + distinct forced with pos==0
    if (blockIdx.x == 0) {
        __shared__ int sc[256];
        sc[tid] = (int)(pCnt[b * NBLK + tid] + pCnt[b * NBLK + tid + 256]);
        __syncthreads();
        for (int s = 128; s > 0; s >>= 1) {
            if (tid < s) sc[tid] += sc[tid + s];
            __syncthreads();
        }
        if (tid == 0) {
            int np = sc[0];
            for (int f = 0; f < M; ++f) {
                int fa = s_fl[f];
                if (fa < 0 || pos[b * A + fa] != 0) continue;
                bool dup = false;
                for (int f2 = 0; f2 < f; ++f2) if (s_fl[f2] == fa) { dup = true; break; }
                if (!dup) ++np;
            }
            atomicExch(&npfix[b], np);
        }
        __syncthreads();
    }

    double csum = 0.0, rsum = 0.0;
    {
        int t = b * A + a;
        float imax = iou_max[t];
        int iarg = iou_arg[t];
        int p = pos[t];
        for (int f = 0; f < M; ++f) if (a == s_fl[f]) p = 1;

        float mwf;
        if (p) {
            const float* row = md + (size_t)t * M;
            mwf = -INFINITY;
#pragma unroll
            for (int m = 0; m < M; ++m) {
                float v = row[m];
                bool pm = (v >= 0.5f) || (a == s_argpos[m]);
                float val = pm ? (1.0f - s_maxpos[m] + v) : (v + v);
                mwf = fmaxf(mwf, val);
            }
        } else {
            mwf = imax + imax;  // max(2*md) == 2*max(md), bit-exact
        }
        double mw = (double)mwf;

        const float* g = ann + ((size_t)(b * M + iarg)) * 6;
        int lab = (int)g[5];
        const float* cp = cls_in + (size_t)t * C;
#pragma unroll
        for (int c = 0; c < C; ++c) {
            double x = (double)cp[c];
            x = fmin(fmax(x, 1e-4), 1.0 - 1e-4);
            double tgt;
            if (p) tgt = (c == lab) ? 1.0 : 0.0;
            else   tgt = (imax < 0.4f) ? 0.0 : -1.0;
            if (tgt >= 0.0) {
                bool one = (tgt == 1.0);
                double af = one ? 0.25 : 0.75;
                double q = one ? (1.0 - x) : x;
                double fw = af * q * q;
                double bce = one ? -log(x + 1e-6) : -log(1.0 - x + 1e-6);
                double sw = one ? (mw + 1.0) : 1.0;
                csum += fw * bce * sw;
            }
        }
        if (p) {
            const float* pa = anc + (size_t)t * 5;
            double gw = fmax((double)g[2], 1.0);
            double gh = fmax((double)g[3], 1.0);
            double rt0 = ((double)g[0] - (double)pa[0]) / (double)pa[2];
            double rt1 = ((double)g[1] - (double)pa[1]) / (double)pa[3];
            double rt2 = log(gw / (double)pa[2]);
            double rt3 = log(gh / (double)pa[3]);
            double rt4 = tan((double)g[4] * (PI_D / 180.0)) - tan((double)pa[4] * (PI_D / 180.0));
            double rt[5] = {rt0, rt1, rt2, rt3, rt4};
            const float* rg = reg_in + (size_t)t * 5;
#pragma unroll
            for (int k = 0; k < 5; ++k) {
                double d = fabs((double)rg[k] - rt[k]);
                double s = (d < (1.0 / 9.0)) ? (0.5 * d * d * 9.0) : (d - 0.5 / 9.0);
                rsum += s * mw;
            }
        }
    }
    __shared__ double scs[256];
    __shared__ double srs[256];
    scs[tid] = csum;
    srs[tid] = rsum;
    __syncthreads();
    for (int s = 128; s > 0; s >>= 1) {
        if (tid < s) { scs[tid] += scs[tid + s]; srs[tid] += srs[tid + s]; }
        __syncthreads();
    }
    if (tid == 0) {
        atomicAdd(&sums[b], scs[0]);
        atomicAdd(&sums[2 + b], srs[0]);
    }

    // ---- final combine: relaxed flag; __syncthreads drains vmcnt so the
    //      sums/npfix atomics above are globally performed before the flag.
    __syncthreads();
    __shared__ int s_last;
    if (tid == 0) s_last = (atomicAdd(&dones[0], 1) == NLOSS - 1) ? 1 : 0;
    __syncthreads();
    if (s_last && tid == 0) {
        double lc = 0.0, lr = 0.0;
        for (int bb = 0; bb < B; ++bb) {
            int np = __hip_atomic_load(&npfix[bb], __ATOMIC_RELAXED, __HIP_MEMORY_SCOPE_AGENT);
            double sc = __hip_atomic_load(&sums[bb], __ATOMIC_RELAXED, __HIP_MEMORY_SCOPE_AGENT);
            double sr = __hip_atomic_load(&sums[2 + bb], __ATOMIC_RELAXED, __HIP_MEMORY_SCOPE_AGENT);
            lc += sc / fmax((double)np, 1.0);
            int denom = np * 5;
            if (denom < 1) denom = 1;
            lr += (np > 0) ? (sr / (double)denom) : 0.0;
        }
        out[0] = (float)(lc / (double)B);
        out[1] = (float)(lr / (double)B);
    }
}

extern "C" void kernel_launch(void* const* d_in, const int* in_sizes, int n_in,
                              void* d_out, int out_size, void* d_ws, size_t ws_size,
                              hipStream_t stream) {
    const float* cls  = (const float*)d_in[0];  // (B, A, C)
    const float* reg  = (const float*)d_in[1];  // (B, A, 5)
    const float* anc  = (const float*)d_in[2];  // (B, A, 5)
    const float* ranc = (const float*)d_in[3];  // (B, A, 5)
    const float* ann  = (const float*)d_in[4];  // (B, M, 6)
    float* out = (float*)d_out;

    char* ws = (char*)d_ws;
    float* md      = (float*)(ws + OFF_MD);
    u32*   list    = (u32*)(ws + OFF_LIST);
    u32*   segcnt  = (u32*)(ws + OFF_SEGC);
    u64*   pAllT   = (u64*)(ws + OFF_PALLT);
    u64*   pPosT   = (u64*)(ws + OFF_PPOST);
    u32*   pCnt    = (u32*)(ws + OFF_PCNT);
    float* iou_max = (float*)(ws + OFF_IOUMAX);
    int*   iou_arg = (int*)(ws + OFF_IOUARG);
    int*   pos     = (int*)(ws + OFF_POS);
    int*   npfix   = (int*)(ws + OFF_NPFIX);
    double* sums   = (double*)(ws + OFF_SUMS);
    int*   dones   = (int*)(ws + OFF_DONES);

    (void)in_sizes; (void)n_in; (void)out_size; (void)ws_size;

    k_gate<<<NGATE, 256, 0, stream>>>(anc, ranc, ann, md, list, segcnt, sums, dones);
    k_geom<<<NGATE / 4, 256, 0, stream>>>(anc, ranc, ann, list, segcnt, md);
    k_assign<<<dim3(NBLK, B), 256, 0, stream>>>(md, iou_max, iou_arg, pos,
                                                pAllT, pPosT, pCnt);
    k_loss<<<dim3(A / 256, B), 256, 0, stream>>>(cls, reg, anc, ann, md, iou_max,
                                                 iou_arg, pos, pAllT, pPosT,
                                                 pCnt, npfix, sums, dones, out);
}

// Round 10
// 125.647 us; speedup vs baseline: 1.1696x; 1.1696x over previous
//
#include <hip/hip_runtime.h>
#include <math.h>

typedef unsigned long long u64;
typedef unsigned int u32;

// Problem constants (fixed by the reference setup_inputs)
static constexpr int A = 16384;
static constexpr int M = 32;
static constexpr int C = 15;
static constexpr int B = 2;
static constexpr int NBLK = A / 32;            // 512 row-tiles per image
static constexpr int NGATE = B * A * M / 256;  // 4096 gate blocks == geom segments
static constexpr int NLOSS = (A / 128) * B;    // 256 loss blocks

static constexpr double PI_D = 3.14159265358979323846;

// ---- workspace layout (bytes) ----
static constexpr size_t OFF_MD     = 0;                                   // f32[B][A][M]   4MB
static constexpr size_t OFF_LIST   = OFF_MD + (size_t)B*A*M*4;            // u32[NGATE][256] 4MB
static constexpr size_t OFF_SEGC   = OFF_LIST + (size_t)NGATE*256*4;      // u32[NGATE]
static constexpr size_t OFF_PALL   = OFF_SEGC + (size_t)NGATE*4;          // u64[B*M][NBLK] 256KB (column-major)
static constexpr size_t OFF_PPOS   = OFF_PALL + (size_t)B*M*NBLK*8;       // u64[B*M][NBLK] 256KB
static constexpr size_t OFF_PCNT   = OFF_PPOS + (size_t)B*M*NBLK*8;       // u32[B*NBLK]    4KB
static constexpr size_t OFF_KEYALL = OFF_PCNT + (size_t)B*NBLK*4;         // u64[B*M]
static constexpr size_t OFF_KEYPOS = OFF_KEYALL + (size_t)B*M*8;          // u64[B*M]
static constexpr size_t OFF_IOUMAX = OFF_KEYPOS + (size_t)B*M*8;          // f32[B][A]
static constexpr size_t OFF_IOUARG = OFF_IOUMAX + (size_t)B*A*4;          // int[B][A]
static constexpr size_t OFF_POS    = OFF_IOUARG + (size_t)B*A*4;          // int[B][A]
static constexpr size_t OFF_NPBASE = OFF_POS + (size_t)B*A*4;             // int[B]
static constexpr size_t OFF_NPFIX  = OFF_NPBASE + (size_t)B*4;            // int[B]
static constexpr size_t OFF_SUMS   = (OFF_NPFIX + (size_t)B*4 + 7) & ~(size_t)7; // double[4]
static constexpr size_t OFF_DONES  = OFF_SUMS + 4*8;                      // int[1]

// ---------- geometry helpers (all double, fully register-resident) ----------
__device__ inline double aa_square_iou(double cx1, double cy1, double s1,
                                       double cx2, double cy2, double s2) {
    double lx = fmax(cx1 - s1, cx2 - s2), ly = fmax(cy1 - s1, cy2 - s2);
    double rx = fmin(cx1 + s1, cx2 + s2), ry = fmin(cy1 + s1, cy2 + s2);
    double w = fmax(rx - lx, 0.0), h = fmax(ry - ly, 0.0);
    double inter = w * h;
    double aa = (2.0 * s1) * (2.0 * s1);
    double ab = (2.0 * s2) * (2.0 * s2);
    return inter / (aa + ab - inter + 1e-8);
}

__device__ inline void rbox_corners1(double cx, double cy, double w, double h,
                                     double adeg, double* X, double* Y) {
    double t = adeg * (PI_D / 180.0);
    double c = cos(t), s = sin(t);
    const double lx[4] = {-0.5, 0.5, 0.5, -0.5};
    const double ly[4] = {-0.5, -0.5, 0.5, 0.5};
#pragma unroll
    for (int i = 0; i < 4; ++i) {
        double dx = w * lx[i], dy = h * ly[i];
        X[i] = cx + dx * c - dy * s;
        Y[i] = cy + dx * s + dy * c;
    }
}

// Interval-clipped boundary integral: area contribution of P's edges inside Q.
__device__ inline double edges_in_quad_cross_sum(const double* PX, const double* PY,
                                                 const double* QX, const double* QY) {
    double s = 0.0;
#pragma unroll
    for (int k = 0; k < 4; ++k) {
        double x0 = PX[k], y0 = PY[k];
        double x1 = PX[(k + 1) & 3], y1 = PY[(k + 1) & 3];
        double ex = x1 - x0, ey = y1 - y0;
        double t0 = 0.0, t1 = 1.0;
        bool empty = false;
#pragma unroll
        for (int e = 0; e < 4; ++e) {
            double qx0 = QX[e], qy0 = QY[e];
            double qex = QX[(e + 1) & 3] - qx0;
            double qey = QY[(e + 1) & 3] - qy0;
            double d0 = qex * (y0 - qy0) - qey * (x0 - qx0);  // >=0 inside (CCW)
            double d1 = qex * (y1 - qy0) - qey * (x1 - qx0);
            if (d0 < 0.0 && d1 < 0.0) empty = true;
            else if (d0 < 0.0) t0 = fmax(t0, d0 / (d0 - d1));
            else if (d1 < 0.0) t1 = fmin(t1, d0 / (d0 - d1));
        }
        if (!empty && t1 > t0) {
            double ax = x0 + t0 * ex, ay = y0 + t0 * ey;
            double bx = x0 + t1 * ex, by = y0 + t1 * ey;
            s += ax * by - ay * bx;
        }
    }
    return s;
}

__device__ inline double quad_inter_area(const double* AX, const double* AY,
                                         const double* BX, const double* BY) {
    double s = edges_in_quad_cross_sum(AX, AY, BX, BY) +
               edges_in_quad_cross_sum(BX, BY, AX, AY);
    return 0.5 * fabs(s);
}

__device__ inline u64 pack_key(float v, u32 inv_idx) {
    return ((u64)__float_as_uint(v) << 32) | (u64)inv_idx;
}

// ---------- kernels ----------
// 1) Gate all 1M pairs; per-block private compaction segments. Zeroes sums/dones.
__global__ void k_gate(const float* __restrict__ anc, const float* __restrict__ ranc,
                       const float* __restrict__ ann, float* __restrict__ md,
                       u32* __restrict__ list, u32* __restrict__ segcnt,
                       double* __restrict__ sums, int* __restrict__ dones) {
    __shared__ u32 l_cnt;
    __shared__ u32 l_idx[256];
    int tid = threadIdx.x;
    if (tid == 0) l_cnt = 0;
    __syncthreads();

    int t = blockIdx.x * 256 + tid;
    if (t < 4) sums[t] = 0.0;
    if (t < 1) dones[0] = 0;
    int m = t & (M - 1);
    int a = (t >> 5) & (A - 1);
    int b = t >> 19;

    const float* pa = anc + ((size_t)(b * A + a)) * 5;
    const float* pr = ranc + ((size_t)(b * A + a)) * 5;
    const float* pg = ann + ((size_t)(b * M + m)) * 6;

    double cxg = pg[0], cyg = pg[1];
    double sg = 0.5 * fmax((double)pg[2], (double)pg[3]);
    double i_bf = aa_square_iou(pa[0], pa[1], 0.5 * fmax((double)pa[2], (double)pa[3]),
                                cxg, cyg, sg);
    double i_af = aa_square_iou(pr[0], pr[1], 0.5 * fmax((double)pr[2], (double)pr[3]),
                                cxg, cyg, sg);
    bool g = (i_bf >= 0.1) || (i_af >= 0.1);
    md[t] = 0.0f;  // gated entries overwritten by k_geom

    if (g) {
        u32 s = atomicAdd(&l_cnt, 1u);  // LDS atomic — per-CU, cheap
        l_idx[s] = (u32)t;
    }
    __syncthreads();
    u32 n = l_cnt;
    if ((u32)tid < n) list[blockIdx.x * 256 + tid] = l_idx[tid];
    if (tid == 0) segcnt[blockIdx.x] = n;
}

// 2) Dense geometry: one wave per gate-segment.
__global__ void k_geom(const float* __restrict__ anc, const float* __restrict__ ranc,
                       const float* __restrict__ ann, const u32* __restrict__ list,
                       const u32* __restrict__ segcnt, float* __restrict__ md) {
    int gtid = blockIdx.x * 256 + threadIdx.x;
    int wave = gtid >> 6;
    int lane = gtid & 63;
    u32 n = segcnt[wave];
    for (u32 i = lane; i < n; i += 64) {
        u32 t = list[wave * 256 + i];
        int m = t & (M - 1);
        int a = ((int)t >> 5) & (A - 1);
        int b = (int)t >> 19;
        const float* pa = anc + ((size_t)(b * A + a)) * 5;
        const float* pr = ranc + ((size_t)(b * A + a)) * 5;
        const float* pg = ann + ((size_t)(b * M + m)) * 6;

        double cxg = pg[0], cyg = pg[1], wg = pg[2], hg = pg[3], ag = pg[4];
        double sg = 0.5 * fmax(wg, hg);
        double cxa = pa[0], cya = pa[1], wa = pa[2], ha = pa[3], aa = pa[4];
        double cxr = pr[0], cyr = pr[1], wr = pr[2], hr = pr[3], ar = pr[4];

        double i_bf = aa_square_iou(cxa, cya, 0.5 * fmax(wa, ha), cxg, cyg, sg);
        double i_af = aa_square_iou(cxr, cyr, 0.5 * fmax(wr, hr), cxg, cyg, sg);

        double GX[4], GY[4];
        rbox_corners1(cxg, cyg, wg, hg, ag, GX, GY);
        double areaG = wg * hg;
        double ov_bf = 0.0, ov_af = 0.0;
        if (i_bf >= 0.1) {
            double X[4], Y[4];
            rbox_corners1(cxa, cya, wa, ha, aa, X, Y);
            double inter = quad_inter_area(X, Y, GX, GY);
            ov_bf = inter / (wa * ha + areaG - inter + 1e-8);
        }
        if (i_af >= 0.1) {
            double X[4], Y[4];
            rbox_corners1(cxr, cyr, wr, hr, ar, X, Y);
            double inter = quad_inter_area(X, Y, GX, GY);
            ov_af = inter / (wr * hr + areaG - inter + 1e-8);
        }
        md[t] = (float)fabs(ov_bf + 0.5 * ov_af - fabs(ov_af - ov_bf));
    }
}

// 3) Assignment: per-tile row max/argmax/pos + COLUMN-MAJOR partials (r6-proven
//    layout: k_cols reads coalesced) + pos counts. Plain writes, zero atomics.
__global__ void k_assign(const float* __restrict__ md,
                         float* __restrict__ iou_max, int* __restrict__ iou_arg,
                         int* __restrict__ pos, u64* __restrict__ pAll,
                         u64* __restrict__ pPos, u32* __restrict__ pCnt) {
    int blk = blockIdx.x, b = blockIdx.y, tid = threadIdx.x;
    int a0 = blk * 32;
    const float4* src = (const float4*)(md + (size_t)(b * A + a0) * M);
    float4 v4 = src[tid];                       // tile [32 rows][32 cols]
    int rr = tid >> 3, c0 = (tid & 7) * 4;
    float vv[4] = {v4.x, v4.y, v4.z, v4.w};

    u64 rowk = 0;
#pragma unroll
    for (int j = 0; j < 4; ++j) {
        u64 k = pack_key(vv[j], 0xFFFFFFFFu - (u32)(c0 + j));
        if (k > rowk) rowk = k;
    }
#pragma unroll
    for (int off = 1; off < 8; off <<= 1) {
        u64 o = __shfl_xor(rowk, off, 8);
        if (o > rowk) rowk = o;
    }
    float rmax = __uint_as_float((u32)(rowk >> 32));
    int p = (rmax >= 0.5f) ? 1 : 0;

    __shared__ u64 lAll[32][33];
    __shared__ u64 lPos[32][33];
    __shared__ int lcnt[32];
    u32 inva = 0xFFFFFFFFu - (u32)(a0 + rr);
#pragma unroll
    for (int j = 0; j < 4; ++j) {
        u64 ck = pack_key(vv[j], inva);
        lAll[rr][c0 + j] = ck;
        lPos[rr][c0 + j] = p ? ck : 0ull;
    }
    if ((tid & 7) == 0) {
        int idx = b * A + a0 + rr;
        iou_max[idx] = rmax;
        iou_arg[idx] = (int)(0xFFFFFFFFu - (u32)(rowk & 0xFFFFFFFFull));
        pos[idx] = p;
        lcnt[rr] = p;
    }
    __syncthreads();
    if (tid < 32) {
        u64 ka = 0, kp = 0;
#pragma unroll
        for (int r = 0; r < 32; ++r) {
            u64 x = lAll[r][tid]; if (x > ka) ka = x;
            u64 y = lPos[r][tid]; if (y > kp) kp = y;
        }
        pAll[((size_t)(b * M + tid)) * NBLK + blk] = ka;
        pPos[((size_t)(b * M + tid)) * NBLK + blk] = kp;
        if (tid == 0) {
            int c = 0;
#pragma unroll
            for (int r = 0; r < 32; ++r) c += lcnt[r];
            pCnt[b * NBLK + blk] = (u32)c;
        }
    }
}

// 3b) Tiny column reduce (r6-proven): coalesced; m==0 also sums pos counts.
__global__ void k_cols(const u64* __restrict__ pAll, const u64* __restrict__ pPos,
                       const u32* __restrict__ pCnt, u64* __restrict__ keyAll,
                       u64* __restrict__ keyPos, int* __restrict__ npbase) {
    int m = blockIdx.x, b = blockIdx.y, tid = threadIdx.x;
    const u64* pa = pAll + ((size_t)(b * M + m)) * NBLK;
    const u64* pp = pPos + ((size_t)(b * M + m)) * NBLK;
    u64 ka = pa[tid], kp = pp[tid];
    u64 ka2 = pa[tid + 256], kp2 = pp[tid + 256];
    if (ka2 > ka) ka = ka2;
    if (kp2 > kp) kp = kp2;
    __shared__ u64 sa[256], sp[256];
    sa[tid] = ka; sp[tid] = kp;
    __syncthreads();
    for (int s = 128; s > 0; s >>= 1) {
        if (tid < s) {
            if (sa[tid + s] > sa[tid]) sa[tid] = sa[tid + s];
            if (sp[tid + s] > sp[tid]) sp[tid] = sp[tid + s];
        }
        __syncthreads();
    }
    if (tid == 0) {
        keyAll[b * M + m] = sa[0];
        keyPos[b * M + m] = sp[0];
    }
    if (m == 0) {
        __shared__ int sc[256];
        sc[tid] = (int)(pCnt[b * NBLK + tid] + pCnt[b * NBLK + tid + 256]);
        __syncthreads();
        for (int s = 128; s > 0; s >>= 1) {
            if (tid < s) sc[tid] += sc[tid + s];
            __syncthreads();
        }
        if (tid == 0) npbase[b] = sc[0];
    }
}

// 4) Loss + final combine. Prologue: 64 broadcast key reads + unrolled forced
//    fold. 256 blocks x 128 threads -> all CUs busy. Relaxed-flag final (r8).
__global__ void k_loss(const float* __restrict__ cls_in, const float* __restrict__ reg_in,
                       const float* __restrict__ anc, const float* __restrict__ ann,
                       const float* __restrict__ md,
                       const float* __restrict__ iou_max, const int* __restrict__ iou_arg,
                       const int* __restrict__ pos,
                       const u64* __restrict__ keyAll, const u64* __restrict__ keyPos,
                       const int* __restrict__ npbase, int* __restrict__ npfix,
                       double* __restrict__ sums, int* __restrict__ dones,
                       float* __restrict__ out) {
    int b = blockIdx.y;
    int tid = threadIdx.x;
    int a = blockIdx.x * 128 + tid;

    __shared__ int s_fl[M];
    __shared__ float s_maxpos[M];
    __shared__ int s_argpos[M];
    if (tid < M) {
        u64 kall = keyAll[b * M + tid];
        float mx = __uint_as_float((u32)(kall >> 32));
        s_fl[tid] = (mx < 0.5f) ? (int)(0xFFFFFFFFu - (u32)(kall & 0xFFFFFFFFull)) : -1;
    }
    __syncthreads();
    if (tid < M) {
        u64 kp = keyPos[b * M + tid];
#pragma unroll
        for (int f = 0; f < M; ++f) {
            int fa = s_fl[f];
            if (fa >= 0) {
                float v = md[((size_t)(b * A + fa)) * M + tid];
                u64 k = pack_key(v, 0xFFFFFFFFu - (u32)fa);
                if (k > kp) kp = k;
            }
        }
        if (kp == 0ull) { s_maxpos[tid] = 0.0f; s_argpos[tid] = -1; }
        else {
            s_maxpos[tid] = __uint_as_float((u32)(kp >> 32));
            s_argpos[tid] = (int)(0xFFFFFFFFu - (u32)(kp & 0xFFFFFFFFull));
        }
    }
    __syncthreads();

    // image num_pos (block x==0 only): base + distinct forced with pos==0
    if (blockIdx.x == 0 && tid == 0) {
        int np = npbase[b];
#pragma unroll
        for (int f = 0; f < M; ++f) {
            int fa = s_fl[f];
            if (fa < 0 || pos[b * A + fa] != 0) continue;
            bool dup = false;
            for (int f2 = 0; f2 < f; ++f2) if (s_fl[f2] == fa) { dup = true; break; }
            if (!dup) ++np;
        }
        atomicExch(&npfix[b], np);
    }

    double csum = 0.0, rsum = 0.0;
    {
        int t = b * A + a;
        float imax = iou_max[t];
        int iarg = iou_arg[t];
        int p = pos[t];
#pragma unroll
        for (int f = 0; f < M; ++f) if (a == s_fl[f]) p = 1;

        float mwf;
        if (p) {
            const float* row = md + (size_t)t * M;
            mwf = -INFINITY;
#pragma unroll
            for (int m = 0; m < M; ++m) {
                float v = row[m];
                bool pm = (v >= 0.5f) || (a == s_argpos[m]);
                float val = pm ? (1.0f - s_maxpos[m] + v) : (v + v);
                mwf = fmaxf(mwf, val);
            }
        } else {
            mwf = imax + imax;  // max(2*md) == 2*max(md), bit-exact
        }
        double mw = (double)mwf;

        const float* g = ann + ((size_t)(b * M + iarg)) * 6;
        int lab = (int)g[5];
        const float* cp = cls_in + (size_t)t * C;
#pragma unroll
        for (int c = 0; c < C; ++c) {
            double x = (double)cp[c];
            x = fmin(fmax(x, 1e-4), 1.0 - 1e-4);
            double tgt;
            if (p) tgt = (c == lab) ? 1.0 : 0.0;
            else   tgt = (imax < 0.4f) ? 0.0 : -1.0;
            if (tgt >= 0.0) {
                bool one = (tgt == 1.0);
                double af = one ? 0.25 : 0.75;
                double q = one ? (1.0 - x) : x;
                double fw = af * q * q;
                double bce = one ? -log(x + 1e-6) : -log(1.0 - x + 1e-6);
                double sw = one ? (mw + 1.0) : 1.0;
                csum += fw * bce * sw;
            }
        }
        if (p) {
            const float* pa = anc + (size_t)t * 5;
            double gw = fmax((double)g[2], 1.0);
            double gh = fmax((double)g[3], 1.0);
            double rt0 = ((double)g[0] - (double)pa[0]) / (double)pa[2];
            double rt1 = ((double)g[1] - (double)pa[1]) / (double)pa[3];
            double rt2 = log(gw / (double)pa[2]);
            double rt3 = log(gh / (double)pa[3]);
            double rt4 = tan((double)g[4] * (PI_D / 180.0)) - tan((double)pa[4] * (PI_D / 180.0));
            double rt[5] = {rt0, rt1, rt2, rt3, rt4};
            const float* rg = reg_in + (size_t)t * 5;
#pragma unroll
            for (int k = 0; k < 5; ++k) {
                double d = fabs((double)rg[k] - rt[k]);
                double s = (d < (1.0 / 9.0)) ? (0.5 * d * d * 9.0) : (d - 0.5 / 9.0);
                rsum += s * mw;
            }
        }
    }
    __shared__ double scs[128];
    __shared__ double srs[128];
    scs[tid] = csum;
    srs[tid] = rsum;
    __syncthreads();
    for (int s = 64; s > 0; s >>= 1) {
        if (tid < s) { scs[tid] += scs[tid + s]; srs[tid] += srs[tid + s]; }
        __syncthreads();
    }
    if (tid == 0) {
        atomicAdd(&sums[b], scs[0]);
        atomicAdd(&sums[2 + b], srs[0]);
    }

    // ---- final combine: relaxed flag (r8-proven); __syncthreads drains vmcnt
    //      so the sums/npfix atomics above are globally performed first.
    __syncthreads();
    __shared__ int s_last;
    if (tid == 0) s_last = (atomicAdd(&dones[0], 1) == NLOSS - 1) ? 1 : 0;
    __syncthreads();
    if (s_last && tid == 0) {
        double lc = 0.0, lr = 0.0;
        for (int bb = 0; bb < B; ++bb) {
            int np = __hip_atomic_load(&npfix[bb], __ATOMIC_RELAXED, __HIP_MEMORY_SCOPE_AGENT);
            double sc = __hip_atomic_load(&sums[bb], __ATOMIC_RELAXED, __HIP_MEMORY_SCOPE_AGENT);
            double sr = __hip_atomic_load(&sums[2 + bb], __ATOMIC_RELAXED, __HIP_MEMORY_SCOPE_AGENT);
            lc += sc / fmax((double)np, 1.0);
            int denom = np * 5;
            if (denom < 1) denom = 1;
            lr += (np > 0) ? (sr / (double)denom) : 0.0;
        }
        out[0] = (float)(lc / (double)B);
        out[1] = (float)(lr / (double)B);
    }
}

extern "C" void kernel_launch(void* const* d_in, const int* in_sizes, int n_in,
                              void* d_out, int out_size, void* d_ws, size_t ws_size,
                              hipStream_t stream) {
    const float* cls  = (const float*)d_in[0];  // (B, A, C)
    const float* reg  = (const float*)d_in[1];  // (B, A, 5)
    const float* anc  = (const float*)d_in[2];  // (B, A, 5)
    const float* ranc = (const float*)d_in[3];  // (B, A, 5)
    const float* ann  = (const float*)d_in[4];  // (B, M, 6)
    float* out = (float*)d_out;

    char* ws = (char*)d_ws;
    float* md      = (float*)(ws + OFF_MD);
    u32*   list    = (u32*)(ws + OFF_LIST);
    u32*   segcnt  = (u32*)(ws + OFF_SEGC);
    u64*   pAll    = (u64*)(ws + OFF_PALL);
    u64*   pPos    = (u64*)(ws + OFF_PPOS);
    u32*   pCnt    = (u32*)(ws + OFF_PCNT);
    u64*   keyAll  = (u64*)(ws + OFF_KEYALL);
    u64*   keyPos  = (u64*)(ws + OFF_KEYPOS);
    float* iou_max = (float*)(ws + OFF_IOUMAX);
    int*   iou_arg = (int*)(ws + OFF_IOUARG);
    int*   pos     = (int*)(ws + OFF_POS);
    int*   npbase  = (int*)(ws + OFF_NPBASE);
    int*   npfix   = (int*)(ws + OFF_NPFIX);
    double* sums   = (double*)(ws + OFF_SUMS);
    int*   dones   = (int*)(ws + OFF_DONES);

    (void)in_sizes; (void)n_in; (void)out_size; (void)ws_size;

    k_gate<<<NGATE, 256, 0, stream>>>(anc, ranc, ann, md, list, segcnt, sums, dones);
    k_geom<<<NGATE / 4, 256, 0, stream>>>(anc, ranc, ann, list, segcnt, md);
    k_assign<<<dim3(NBLK, B), 256, 0, stream>>>(md, iou_max, iou_arg, pos,
                                                pAll, pPos, pCnt);
    k_cols<<<dim3(M, B), 256, 0, stream>>>(pAll, pPos, pCnt, keyAll, keyPos, npbase);
    k_loss<<<dim3(A / 128, B), 128, 0, stream>>>(cls, reg, anc, ann, md, iou_max,
                                                 iou_arg, pos, keyAll, keyPos,
                                                 npbase, npfix, sums, dones, out);
}